// Round 4
// baseline (634.824 us; speedup 1.0000x reference)
//
#include <hip/hip_runtime.h>

#define BB 512
#define V0 1024
#define V1 256
#define E0 8192
#define E1 2048

// ---------------- CSR build (deterministic) ----------------
__global__ void k_deg(const int* __restrict__ rows, int E, int* __restrict__ deg) {
    int t = blockIdx.x * 256 + threadIdx.x;
    if (t < E) atomicAdd(&deg[rows[t]], 1);
}

__global__ void k_scan(const int* __restrict__ deg, int* __restrict__ off, int V) {
    __shared__ int s[1024];
    int t = threadIdx.x;
    s[t] = (t < V) ? deg[t] : 0;
    __syncthreads();
    for (int d = 1; d < 1024; d <<= 1) {
        int val = (t >= d) ? s[t - d] : 0;
        __syncthreads();
        s[t] += val;
        __syncthreads();
    }
    if (t < V) off[t + 1] = s[t];
    if (t == 0) off[0] = 0;
}

// stable fill: edge e goes to off[row] + (#earlier edges with same row)
__global__ void k_fill(const int* __restrict__ rows, const int* __restrict__ cols,
                       const float* __restrict__ vals, int E,
                       const int* __restrict__ off, int* __restrict__ scol,
                       float* __restrict__ sval) {
    __shared__ int rs[256];
    int e = blockIdx.x * 256 + threadIdx.x;
    int r = (e < E) ? rows[e] : -1;
    int rank = 0;
    for (int c0 = 0; c0 <= (int)blockIdx.x; ++c0) {
        __syncthreads();
        int idx = c0 * 256 + threadIdx.x;
        rs[threadIdx.x] = (idx < E) ? rows[idx] : -2;
        __syncthreads();
        int lim = e - c0 * 256;
        if (lim > 256) lim = 256;
        for (int j = 0; j < lim; ++j) rank += (rs[j] == r) ? 1 : 0;
    }
    if (e < E) {
        int p = off[r] + rank;
        scol[p] = cols[e];
        sval[p] = vals[e];
    }
}

// ---------------- fused cheby conv: 1 thread = 1 (batch,vertex) column ----------------
// xin [B, V, FIN], out [B, V or V/4, FOUT]. Block covers NB batches x V vertices.
// LDS: two vertex-major slabs (x0, x1), XOR-swizzled 16B units; Wl broadcast panel.
// Thread keeps x0/x1/x2 of its own column in registers; GEMM acc[FOUT] in registers.
// POOL: 0 = none, 1 = quad-lane shfl max (pool over 4 consecutive vertices).
template <int V, int NB, int FIN, int FH, int FOUT, int POOL>
__global__ __launch_bounds__(NB * V, 4) void k_conv(
    const float* __restrict__ xin, const float* __restrict__ W,
    const float* __restrict__ bias, float* __restrict__ out,
    const int* __restrict__ off, const int* __restrict__ scol,
    const float* __restrict__ sval) {
    constexpr int NPH = FIN / FH;
    constexpr int NC = NB * V;
    constexpr bool SC3 = (FH == 3);
    constexpr int Q = SC3 ? 1 : FH / 4;          // 16B units per column
    constexpr int SLAB = SC3 ? NC * 3 : NC * FH; // floats per slab
    __shared__ float xs[2 * SLAB];
    __shared__ float Wl[3 * FH * FOUT];

    const int t = threadIdx.x;
    const int bb = (NB == 1) ? 0 : (t / V);
    const int vloc = (NB == 1) ? t : (t - bb * V);
    const int b = blockIdx.x * NB + bb;
    const int colg = bb * V;
    const int col = t;
    const int s0 = off[vloc], e0 = off[vloc + 1];

    float acc[FOUT];
#pragma unroll
    for (int o = 0; o < FOUT; ++o) acc[o] = 0.f;

#define GEMM_STEP(UVAL, KK)                                              \
    {                                                                    \
        const float uv_ = (UVAL);                                        \
        _Pragma("unroll") for (int j_ = 0; j_ < FOUT / 4; ++j_) {        \
            float4 wv_ = *(const float4*)&Wl[(KK) * FOUT + 4 * j_];      \
            acc[4 * j_ + 0] += uv_ * wv_.x;                              \
            acc[4 * j_ + 1] += uv_ * wv_.y;                              \
            acc[4 * j_ + 2] += uv_ * wv_.z;                              \
            acc[4 * j_ + 3] += uv_ * wv_.w;                              \
        }                                                                \
    }

    for (int ph = 0; ph < NPH; ++ph) {
        // ---- transformed weight panels (k-major [k][o]): W0-W2 | W1 | 2*W2
        for (int idx = t; idx < FH * FOUT; idx += NC) {
            int f = idx / FOUT, o = idx - f * FOUT;
            int fg = ph * FH + f;
            float w0 = W[o * (3 * FIN) + fg * 3 + 0];
            float w1 = W[o * (3 * FIN) + fg * 3 + 1];
            float w2 = W[o * (3 * FIN) + fg * 3 + 2];
            Wl[f * FOUT + o] = w0 - w2;
            Wl[(FH + f) * FOUT + o] = w1;
            Wl[(2 * FH + f) * FOUT + o] = 2.f * w2;
        }
        float x0r[FH], x1r[FH], x2r[FH];
        // ---- stage x0 slice (retain own column in regs)
        if constexpr (SC3) {
#pragma unroll
            for (int f = 0; f < 3; ++f) {
                x0r[f] = xin[((size_t)b * V + vloc) * 3 + f];
                xs[col * 3 + f] = x0r[f];
            }
        } else {
#pragma unroll
            for (int g = 0; g < Q; ++g) {
                float4 q = *(const float4*)(xin + ((size_t)b * V + vloc) * FIN + ph * FH + 4 * g);
                x0r[4 * g + 0] = q.x; x0r[4 * g + 1] = q.y;
                x0r[4 * g + 2] = q.z; x0r[4 * g + 3] = q.w;
                int ui = col * Q + (g ^ ((col >> 2) & (Q - 1)));
                *(float4*)&xs[ui * 4] = q;
            }
        }
        __syncthreads();
        // ---- x1 = L x0 (gather slab0)
#pragma unroll
        for (int f = 0; f < FH; ++f) x1r[f] = 0.f;
        for (int p = s0; p < e0; ++p) {
            int c = colg + scol[p];
            float w = sval[p];
            if constexpr (SC3) {
#pragma unroll
                for (int f = 0; f < 3; ++f) x1r[f] += w * xs[c * 3 + f];
            } else {
#pragma unroll
                for (int g = 0; g < Q; ++g) {
                    int ui = c * Q + (g ^ ((c >> 2) & (Q - 1)));
                    float4 q = *(const float4*)&xs[ui * 4];
                    x1r[4 * g + 0] += w * q.x; x1r[4 * g + 1] += w * q.y;
                    x1r[4 * g + 2] += w * q.z; x1r[4 * g + 3] += w * q.w;
                }
            }
        }
        // ---- publish x1 to slab1
        if constexpr (SC3) {
#pragma unroll
            for (int f = 0; f < 3; ++f) xs[SLAB + col * 3 + f] = x1r[f];
        } else {
#pragma unroll
            for (int g = 0; g < Q; ++g) {
                int ui = col * Q + (g ^ ((col >> 2) & (Q - 1)));
                float4 q = {x1r[4 * g + 0], x1r[4 * g + 1], x1r[4 * g + 2], x1r[4 * g + 3]};
                *(float4*)&xs[SLAB + ui * 4] = q;
            }
        }
        __syncthreads();
        // ---- x2raw = L x1 (gather slab1)
#pragma unroll
        for (int f = 0; f < FH; ++f) x2r[f] = 0.f;
        for (int p = s0; p < e0; ++p) {
            int c = colg + scol[p];
            float w = sval[p];
            if constexpr (SC3) {
#pragma unroll
                for (int f = 0; f < 3; ++f) x2r[f] += w * xs[SLAB + c * 3 + f];
            } else {
#pragma unroll
                for (int g = 0; g < Q; ++g) {
                    int ui = c * Q + (g ^ ((c >> 2) & (Q - 1)));
                    float4 q = *(const float4*)&xs[SLAB + ui * 4];
                    x2r[4 * g + 0] += w * q.x; x2r[4 * g + 1] += w * q.y;
                    x2r[4 * g + 2] += w * q.z; x2r[4 * g + 3] += w * q.w;
                }
            }
        }
        // ---- GEMM accumulate (weights broadcast from LDS, operand in regs)
#pragma unroll
        for (int k = 0; k < FH; ++k) GEMM_STEP(x0r[k], k);
#pragma unroll
        for (int k = 0; k < FH; ++k) GEMM_STEP(x1r[k], FH + k);
#pragma unroll
        for (int k = 0; k < FH; ++k) GEMM_STEP(x2r[k], 2 * FH + k);
        __syncthreads();  // before next phase overwrites slabs / Wl
    }
#undef GEMM_STEP

    // ---- epilogue
    if constexpr (POOL == 0) {
        float* orow = out + ((size_t)b * V + vloc) * FOUT;
#pragma unroll
        for (int j = 0; j < FOUT / 4; ++j) {
            float4 st;
            st.x = acc[4 * j + 0] + bias[4 * j + 0];
            st.y = acc[4 * j + 1] + bias[4 * j + 1];
            st.z = acc[4 * j + 2] + bias[4 * j + 2];
            st.w = acc[4 * j + 3] + bias[4 * j + 3];
            ((float4*)orow)[j] = st;
        }
    } else {
#pragma unroll
        for (int o = 0; o < FOUT; ++o) {
            float m = acc[o];
            m = fmaxf(m, __shfl_xor(m, 1));
            m = fmaxf(m, __shfl_xor(m, 2));
            acc[o] = m + bias[o];
        }
        const int r = vloc & 3;
        const int vt = vloc >> 2;
        float* orow = out + ((size_t)b * (V / 4) + vt) * FOUT + r * (FOUT / 4);
#pragma unroll
        for (int rq = 0; rq < 4; ++rq) {
            if (r == rq) {
#pragma unroll
                for (int jj = 0; jj < FOUT / 16; ++jj) {
                    float4 st = {acc[rq * (FOUT / 4) + 4 * jj + 0],
                                 acc[rq * (FOUT / 4) + 4 * jj + 1],
                                 acc[rq * (FOUT / 4) + 4 * jj + 2],
                                 acc[rq * (FOUT / 4) + 4 * jj + 3]};
                    ((float4*)orow)[jj] = st;
                }
            }
        }
    }
}

// ---------------- FC1: C[512,512] = A[512,4096] * W[512,4096]^T, split-K=16 ----------------
__global__ __launch_bounds__(256) void k_fc1(const float* __restrict__ A,
                                             const float* __restrict__ W,
                                             float* __restrict__ part) {
    __shared__ float As[16][128];
    __shared__ float Bs[16][128];
    const int tid = threadIdx.x;
    const int bm = blockIdx.x, bn = blockIdx.y, bz = blockIdx.z;
    const int m0 = (tid >> 4) << 3;
    const int n0 = (tid & 15) << 3;
    float acc[8][8];
#pragma unroll
    for (int i = 0; i < 8; ++i)
#pragma unroll
        for (int j = 0; j < 8; ++j) acc[i][j] = 0.f;
    const int r = tid >> 1;
    const int c8 = (tid & 1) << 3;
    const float* Ar = A + (size_t)(bm * 128 + r) * 4096 + bz * 256 + c8;
    const float* Wr = W + (size_t)(bn * 128 + r) * 4096 + bz * 256 + c8;
    for (int kt = 0; kt < 256; kt += 16) {
        float4 a0 = *(const float4*)(Ar + kt);
        float4 a1 = *(const float4*)(Ar + kt + 4);
        float4 w0 = *(const float4*)(Wr + kt);
        float4 w1 = *(const float4*)(Wr + kt + 4);
        __syncthreads();
        As[c8 + 0][r] = a0.x; As[c8 + 1][r] = a0.y; As[c8 + 2][r] = a0.z; As[c8 + 3][r] = a0.w;
        As[c8 + 4][r] = a1.x; As[c8 + 5][r] = a1.y; As[c8 + 6][r] = a1.z; As[c8 + 7][r] = a1.w;
        Bs[c8 + 0][r] = w0.x; Bs[c8 + 1][r] = w0.y; Bs[c8 + 2][r] = w0.z; Bs[c8 + 3][r] = w0.w;
        Bs[c8 + 4][r] = w1.x; Bs[c8 + 5][r] = w1.y; Bs[c8 + 6][r] = w1.z; Bs[c8 + 7][r] = w1.w;
        __syncthreads();
#pragma unroll
        for (int k = 0; k < 16; ++k) {
            float am[8], bn_[8];
            *(float4*)&am[0] = *(const float4*)&As[k][m0];
            *(float4*)&am[4] = *(const float4*)&As[k][m0 + 4];
            *(float4*)&bn_[0] = *(const float4*)&Bs[k][n0];
            *(float4*)&bn_[4] = *(const float4*)&Bs[k][n0 + 4];
#pragma unroll
            for (int i = 0; i < 8; ++i)
#pragma unroll
                for (int j = 0; j < 8; ++j) acc[i][j] += am[i] * bn_[j];
        }
    }
    float* P = part + ((size_t)bz * 512 + bm * 128 + m0) * 512 + bn * 128 + n0;
#pragma unroll
    for (int i = 0; i < 8; ++i) {
        float4 s0 = {acc[i][0], acc[i][1], acc[i][2], acc[i][3]};
        float4 s1 = {acc[i][4], acc[i][5], acc[i][6], acc[i][7]};
        *(float4*)(P + i * 512) = s0;
        *(float4*)(P + i * 512 + 4) = s1;
    }
}

__global__ void k_fc1red(const float* __restrict__ part, const float* __restrict__ bias,
                         float* __restrict__ out) {
    int t = blockIdx.x * 256 + threadIdx.x;  // 512*512
    float s = bias[t & 511];
#pragma unroll
    for (int z = 0; z < 16; ++z) s += part[(size_t)z * 262144 + t];
    out[t] = s;
}

// ---------------- FC2: out[512,63] ----------------
__global__ void k_fc2(const float* __restrict__ X, const float* __restrict__ W,
                      const float* __restrict__ bias, float* __restrict__ out) {
    int b = blockIdx.x, c = threadIdx.x;
    if (c >= 63) return;
    const float4* xr = (const float4*)(X + b * 512);
    const float4* wr = (const float4*)(W + c * 512);
    float s = 0.f;
    for (int k = 0; k < 128; ++k) {
        float4 xv = xr[k], wv = wr[k];
        s += xv.x * wv.x + xv.y * wv.y + xv.z * wv.z + xv.w * wv.w;
    }
    out[b * 63 + c] = s + bias[c];
}

extern "C" void kernel_launch(void* const* d_in, const int* in_sizes, int n_in,
                              void* d_out, int out_size, void* d_ws, size_t ws_size,
                              hipStream_t stream) {
    const float* x = (const float*)d_in[0];
    const int* rows0 = (const int*)d_in[1];
    const int* cols0 = (const int*)d_in[2];
    const float* vals0 = (const float*)d_in[3];
    const int* rows1 = (const int*)d_in[4];
    const int* cols1 = (const int*)d_in[5];
    const float* vals1 = (const float*)d_in[6];
    const float* W0 = (const float*)d_in[7];  const float* b0 = (const float*)d_in[8];
    const float* W1 = (const float*)d_in[9];  const float* b1 = (const float*)d_in[10];
    const float* W2 = (const float*)d_in[11]; const float* b2 = (const float*)d_in[12];
    const float* W3 = (const float*)d_in[13]; const float* b3 = (const float*)d_in[14];
    const float* fcW1 = (const float*)d_in[15]; const float* fcb1 = (const float*)d_in[16];
    const float* fcW2 = (const float*)d_in[17]; const float* fcb2 = (const float*)d_in[18];
    float* out = (float*)d_out;

    float* wsf = (float*)d_ws;
    // CSR region (aliased ints/floats), 65536 floats
    int* off0 = (int*)(wsf + 0);          // 1025
    int* scol0 = (int*)(wsf + 2048);      // 8192
    float* sval0 = wsf + 10240;           // 8192
    int* off1 = (int*)(wsf + 18432);      // 257
    int* scol1 = (int*)(wsf + 20480);     // 2048
    float* sval1 = wsf + 22528;           // 2048
    int* deg0 = (int*)(wsf + 24576);      // 1024
    int* deg1 = (int*)(wsf + 25600);      // 256

    float* A1  = wsf + 65536;             // 16,777,216  [B,1024,32]
    float* P1  = A1 + 16777216;           //  4,194,304  [B,256,32]
    float* A3  = P1 + 4194304;            //  8,388,608  [B,256,64]
    float* FCB = A3 + 8388608;            //  2,097,152  [B,4096]
    float* PART = FCB + 2097152;          //  4,194,304  [16,512,512]
    float* FC1O = PART + 4194304;         //    262,144  [512,512]
    (void)in_sizes; (void)n_in; (void)out_size; (void)ws_size;

    hipMemsetAsync(wsf, 0, 65536 * 4, stream);
    k_deg<<<E0 / 256, 256, 0, stream>>>(rows0, E0, deg0);
    k_deg<<<E1 / 256, 256, 0, stream>>>(rows1, E1, deg1);
    k_scan<<<1, 1024, 0, stream>>>(deg0, off0, V0);
    k_scan<<<1, 1024, 0, stream>>>(deg1, off1, V1);
    k_fill<<<E0 / 256, 256, 0, stream>>>(rows0, cols0, vals0, E0, off0, scol0, sval0);
    k_fill<<<E1 / 256, 256, 0, stream>>>(rows1, cols1, vals1, E1, off1, scol1, sval1);

    // conv1: level0, 3->32             LDS 25.7 KB
    k_conv<V0, 1, 3, 3, 32, 0><<<BB, 1024, 0, stream>>>(x, W0, b0, A1, off0, scol0, sval0);
    // conv2+pool: level0, 32->32       LDS 67 KB
    k_conv<V0, 1, 32, 8, 32, 1><<<BB, 1024, 0, stream>>>(A1, W1, b1, P1, off0, scol0, sval0);
    // conv3: level1, 32->64, NB=2      LDS 38 KB, 256 blocks
    k_conv<V1, 2, 32, 8, 64, 0><<<BB / 2, 512, 0, stream>>>(P1, W2, b2, A3, off1, scol1, sval1);
    // conv4+pool: level1, 64->64, NB=2 LDS 38 KB, 256 blocks
    k_conv<V1, 2, 64, 8, 64, 1><<<BB / 2, 512, 0, stream>>>(A3, W3, b3, FCB, off1, scol1, sval1);

    // head (FCB is [B, 4096] in reference order)
    k_fc1<<<dim3(4, 4, 16), 256, 0, stream>>>(FCB, fcW1, PART);
    k_fc1red<<<1024, 256, 0, stream>>>(PART, fcb1, FC1O);
    k_fc2<<<BB, 64, 0, stream>>>(FC1O, fcW2, fcb2, out);
}